// Round 9
// baseline (114.095 us; speedup 1.0000x reference)
//
#include <hip/hip_runtime.h>

#define NB 8192
#define GPB 4                  // batches per block (serial, pipelined)
#define OT_ELEMS (NB * 1024)   // floats of Ot, then Mt
#define EPSF 1e-10f

typedef __attribute__((ext_vector_type(4))) float f32x4;
typedef __attribute__((ext_vector_type(8))) short s16x8;   // 8 bf16 (4 VGPRs)

// Compile-time scheduling fence (nothing crosses) + runtime LDS-queue drain.
// NO "memory" clobber: SIInsertWaitcnts then does NOT force a vmcnt(0) drain,
// so global loads/stores stay in flight across LDS phases. DS ordering is
// guaranteed by: sched_barrier pins program order, lgkmcnt(0) completes all
// prior DS ops before any later DS op issues.
#define SBAR() __builtin_amdgcn_sched_barrier(0)
#define LGK()  do { SBAR(); asm volatile("s_waitcnt lgkmcnt(0)"); SBAR(); } while (0)

#define MFMA_B16(A, B, C) __builtin_amdgcn_mfma_f32_16x16x32_bf16((A), (B), (C), 0, 0, 0)

// ---------------- Kernel 1: Cayley matrices M = (I-S)^-1 (I+S), stored ROW-major ----------------
__global__ void cayley_kernel(const float* __restrict__ Br,
                              const float* __restrict__ Bt,
                              const float* __restrict__ By,
                              float* __restrict__ M_out) {
  __shared__ float A[32][33];
  __shared__ float R[32][33];
  const float* B = (blockIdx.x == 0) ? Br : (blockIdx.x == 1) ? Bt : By;
  const int t = threadIdx.x;
  const int i = t >> 5, j = t & 31;
  float Lij = (j < i) ? B[i - 1 + j] : 0.0f;
  float Lji = (i < j) ? B[j - 1 + i] : 0.0f;
  float S = Lij - Lji;
  float eye = (i == j) ? 1.0f : 0.0f;
  A[i][j] = eye - S;   // I - S
  R[i][j] = eye + S;   // I + S
  __syncthreads();
  for (int p = 0; p < 32; ++p) {
    float f = A[i][p] / A[p][p];
    __syncthreads();
    if (i != p) {
      A[i][j] -= f * A[p][j];
      R[i][j] -= f * R[p][j];
    }
    __syncthreads();
  }
  // ROW-major: M_out[blk][i*32+j] = M[i][j]  (slot0=MR, slot1=MT, slot2=MY)
  M_out[blockIdx.x * 1024 + i * 32 + j] = R[i][j] / A[i][i];
}

// fp32 -> bf16 hi/lo split (hi = truncated top 16 bits; lo = next 8+ mantissa bits)
__device__ __forceinline__ void cvt_hilo8(const f32x4 f0, const f32x4 f1, s16x8& hi, s16x8& lo) {
  float f[8];
#pragma unroll
  for (int e = 0; e < 4; ++e) { f[e] = f0[e]; f[4 + e] = f1[e]; }
#pragma unroll
  for (int e = 0; e < 8; ++e) {
    unsigned u = __float_as_uint(f[e]);
    hi[e] = (short)(u >> 16);
    float ah = __uint_as_float(u & 0xffff0000u);
    lo[e] = (short)(__float_as_uint(f[e] - ah) >> 16);
  }
}

__device__ __forceinline__ void read_frag_lds(const float* sb, int off, s16x8& hi, s16x8& lo) {
  f32x4 f0 = *(const f32x4*)(sb + off);
  f32x4 f1 = *(const f32x4*)(sb + off + 4);
  cvt_hilo8(f0, f1, hi, lo);
}

// ---- one congruence  out = M * in * M^T, rowtile in / rowtile out (R5-R8 verified layout) ----
// rowtile: lane holds rows i0..i0+3 (i0=(lane>>3)*4) x cols j0..j0+3 (j0=(lane&7)*4).
// Mh/Ml: A-op fragments of M; identical registers serve as B-op fragments of M^T.
__device__ __forceinline__ void congruence_rt(float* sb, int lane,
                                              const s16x8 (&Mh)[2], const s16x8 (&Ml)[2],
                                              const f32x4 (&in)[4], f32x4 (&outr)[4]) {
  const int l15 = lane & 15, l4 = lane >> 4;
  const int i0 = (lane >> 3) << 2, j0 = (lane & 7) << 2;
  // stage `in` COL-major (stride 36): addr = col*36 + row (register transpose)
#pragma unroll
  for (int c = 0; c < 4; ++c) {
    f32x4 colv = {in[0][c], in[1][c], in[2][c], in[3][c]};
    *(f32x4*)(sb + (j0 + c) * 36 + i0) = colv;
  }
  LGK();
  // B-frags of `in`: in[k][col], 8 consecutive k at col-major addr
  s16x8 Bh[2], Bl[2];
#pragma unroll
  for (int s = 0; s < 2; ++s)
    read_frag_lds(sb, (16 * s + l15) * 36 + 8 * l4, Bh[s], Bl[s]);
  LGK();
  // g = M * in
  f32x4 g[2][2];
#pragma unroll
  for (int ms = 0; ms < 2; ++ms)
#pragma unroll
    for (int ns = 0; ns < 2; ++ns) {
      f32x4 acc = {0.f, 0.f, 0.f, 0.f};
      acc = MFMA_B16(Ml[ms], Bh[ns], acc);
      acc = MFMA_B16(Mh[ms], Bl[ns], acc);
      acc = MFMA_B16(Mh[ms], Bh[ns], acc);
      g[ms][ns] = acc;
    }
  // stage g ROW-major (stride 36)
#pragma unroll
  for (int ms = 0; ms < 2; ++ms)
#pragma unroll
    for (int ns = 0; ns < 2; ++ns)
#pragma unroll
      for (int r = 0; r < 4; ++r)
        sb[(16 * ms + 4 * l4 + r) * 36 + 16 * ns + l15] = g[ms][ns][r];
  LGK();
  // A-frags of g
  s16x8 Ah[2], Al[2];
#pragma unroll
  for (int s = 0; s < 2; ++s)
    read_frag_lds(sb, (16 * s + l15) * 36 + 8 * l4, Ah[s], Al[s]);
  LGK();
  // o = g * M^T
  f32x4 o[2][2];
#pragma unroll
  for (int ms = 0; ms < 2; ++ms)
#pragma unroll
    for (int ns = 0; ns < 2; ++ns) {
      f32x4 acc = {0.f, 0.f, 0.f, 0.f};
      acc = MFMA_B16(Al[ms], Mh[ns], acc);
      acc = MFMA_B16(Ah[ms], Ml[ns], acc);
      acc = MFMA_B16(Ah[ms], Mh[ns], acc);
      o[ms][ns] = acc;
    }
  // C-layout -> rowtile through LDS
#pragma unroll
  for (int ms = 0; ms < 2; ++ms)
#pragma unroll
    for (int ns = 0; ns < 2; ++ns)
#pragma unroll
      for (int r = 0; r < 4; ++r)
        sb[(16 * ms + 4 * l4 + r) * 36 + 16 * ns + l15] = o[ms][ns][r];
  LGK();
#pragma unroll
  for (int r = 0; r < 4; ++r)
    outr[r] = *(const f32x4*)(sb + (i0 + r) * 36 + j0);
  LGK();
}

// ---------------- Kernel 2: 4 batches per wave, serial with state prefetch pipeline ----------------
__global__ __launch_bounds__(64) void spdsru_main(
    const float* __restrict__ X, const float* __restrict__ state,
    const float* __restrict__ WR, const float* __restrict__ Wt,
    const float* __restrict__ Wphi, const float* __restrict__ Ws,
    const float* __restrict__ Mg, float* __restrict__ out) {
  __shared__ __align__(16) float sb[1184];
  const int lane = threadIdx.x;
  const int l15 = lane & 15, l4 = lane >> 4;
  const int i0 = (lane >> 3) << 2, j0 = (lane & 7) << 2;
  // XCD-contiguous swizzle: 2048 blocks, xcd = bid&7 gets contiguous 256-block range.
  const int bid = blockIdx.x;
  const int batch0 = ((bid & 7) * (NB / GPB / 8) + (bid >> 3)) * GPB;

  // M fragments from global (row-major M)
  s16x8 Mh[3][2], Ml[3][2];
#pragma unroll
  for (int q = 0; q < 3; ++q)
#pragma unroll
    for (int s = 0; s < 2; ++s) {
      const float* p = Mg + q * 1024 + (16 * s + l15) * 32 + 8 * l4;
      cvt_hilo8(*(const f32x4*)p, *(const f32x4*)(p + 4), Mh[q][s], Ml[q][s]);
    }

  // uniform scalar weights
  const float alpha[5] = {0.01f, 0.25f, 0.5f, 0.9f, 0.99f};
  float wr[5], wsn[5];
  {
    float sR = 0.f, sS = 0.f;
#pragma unroll
    for (int a = 0; a < 5; ++a) { float v = WR[a]; wr[a] = v * v; sR += v * v; }
#pragma unroll
    for (int a = 0; a < 5; ++a) { float v = Ws[a]; wsn[a] = v * v; sS += v * v; }
    const float invR = 1.0f / (sR + EPSF), invS = 1.0f / (sS + EPSF);
#pragma unroll
    for (int a = 0; a < 5; ++a) { wr[a] *= invR; wsn[a] *= invS; }
  }
  const float wt2 = Wt[0] * Wt[0], wp2 = Wphi[0] * Wphi[0];
  const float at = wt2 / (wt2 + wp2 + EPSF);
  const float omat = 1.0f - at;

  // prologue: issue state loads for batch0 (stay in flight)
  f32x4 raw[20];
  {
    const float* stp = state + (size_t)batch0 * 5120;
#pragma unroll
    for (int a = 0; a < 5; ++a)
#pragma unroll
      for (int r = 0; r < 4; ++r)
        raw[a * 4 + r] = *(const f32x4*)(stp + a * 1024 + (i0 + r) * 32 + j0);
  }

#pragma unroll 1
  for (int g = 0; g < GPB; ++g) {
    const int batch = batch0 + g;
    const float* stg = state + (size_t)batch * 5120;

    // fold U = Yt from prefetched raw state (vmcnt waits land here)
    f32x4 U[4];
#pragma unroll
    for (int r = 0; r < 4; ++r) {
      f32x4 u = wr[0] * raw[r];
#pragma unroll
      for (int a = 1; a < 5; ++a) u += wr[a] * raw[a * 4 + r];
      U[r] = u;
    }

    // issue X load (consumed after C1) and next batch's state prefetch (consumed next iter)
    const float* xp = X + (size_t)batch * 1024;
    f32x4 x[4];
#pragma unroll
    for (int r = 0; r < 4; ++r)
      x[r] = __builtin_nontemporal_load((const f32x4*)(xp + (i0 + r) * 32 + j0));
    if (g + 1 < GPB) {
      const float* stn = stg + 5120;
#pragma unroll
      for (int a = 0; a < 5; ++a)
#pragma unroll
        for (int r = 0; r < 4; ++r)
          raw[a * 4 + r] = *(const f32x4*)(stn + a * 1024 + (i0 + r) * 32 + j0);
    }

    // C1: Rt = MR U MR^T ; Tt = (1-at)X + at*Rt
    f32x4 rt[4];
    congruence_rt(sb, lane, Mh[0], Ml[0], U, rt);
    f32x4 tt[4];
#pragma unroll
    for (int r = 0; r < 4; ++r) tt[r] = omat * x[r] + at * rt[r];

    // C2: Phit = MT Tt MT^T
    f32x4 ph[4];
    congruence_rt(sb, lane, Mh[1], Ml[1], tt, ph);

    // EMA: re-read state (L2/L3-hot), NT-write Mt, accumulate St
    float* outMt = out + OT_ELEMS + (size_t)batch * 5120;
    f32x4 st[4];
#pragma unroll
    for (int r = 0; r < 4; ++r) st[r] = f32x4{0.f, 0.f, 0.f, 0.f};
#pragma unroll
    for (int a = 0; a < 5; ++a) {
      const float al = alpha[a], om = 1.0f - al, ws = wsn[a];
#pragma unroll
      for (int r = 0; r < 4; ++r) {
        const f32x4 v = *(const f32x4*)(stg + a * 1024 + (i0 + r) * 32 + j0);
        f32x4 w = om * v + al * ph[r];
        __builtin_nontemporal_store(w, (f32x4*)(outMt + a * 1024 + (i0 + r) * 32 + j0));
        st[r] += ws * w;
      }
    }

    // C3: Ot = MY St MY^T
    f32x4 ot[4];
    congruence_rt(sb, lane, Mh[2], Ml[2], st, ot);
    float* outOt = out + (size_t)batch * 1024;
#pragma unroll
    for (int r = 0; r < 4; ++r)
      __builtin_nontemporal_store(ot[r], (f32x4*)(outOt + (i0 + r) * 32 + j0));
  }
}

extern "C" void kernel_launch(void* const* d_in, const int* in_sizes, int n_in,
                              void* d_out, int out_size, void* d_ws, size_t ws_size,
                              hipStream_t stream) {
  const float* X     = (const float*)d_in[0];
  const float* state = (const float*)d_in[1];
  const float* WR    = (const float*)d_in[2];
  const float* Wt    = (const float*)d_in[3];
  const float* Wphi  = (const float*)d_in[4];
  const float* Ws    = (const float*)d_in[5];
  const float* Br    = (const float*)d_in[6];
  const float* Bt    = (const float*)d_in[7];
  const float* By    = (const float*)d_in[8];
  float* m_ws = (float*)d_ws;   // 3*1024 floats: MR, MT, MY (row-major)
  float* outp = (float*)d_out;

  cayley_kernel<<<3, 1024, 0, stream>>>(Br, Bt, By, m_ws);
  spdsru_main<<<NB / GPB, 64, 0, stream>>>(X, state, WR, Wt, Wphi, Ws, m_ws, outp);
}

// Round 10
// 94.587 us; speedup vs baseline: 1.2062x; 1.2062x over previous
//
#include <hip/hip_runtime.h>

#define NB 8192
#define OT_ELEMS (NB * 1024)   // floats of Ot, then Mt
#define EPSF 1e-10f

typedef __attribute__((ext_vector_type(4))) float f32x4;
typedef __attribute__((ext_vector_type(8))) short s16x8;   // 8 bf16 (4 VGPRs)

// Wave-local DS phase fence WITHOUT a "memory" clobber: sched_barrier(0) pins
// compile-time order (nothing crosses), lgkmcnt(0) drains only the LDS queue.
// Global loads/stores stay in flight across LDS phases (no forced vmcnt(0)).
// Replay-safety of exactly this construct verified in R9 (passed post-timing).
#define SBAR() __builtin_amdgcn_sched_barrier(0)
#define LGK()  do { SBAR(); asm volatile("s_waitcnt lgkmcnt(0)"); SBAR(); } while (0)

#define MFMA_B16(A, B, C) __builtin_amdgcn_mfma_f32_16x16x32_bf16((A), (B), (C), 0, 0, 0)

// ---------------- Kernel 1: Cayley matrices M = (I-S)^-1 (I+S), stored ROW-major ----------------
__global__ void cayley_kernel(const float* __restrict__ Br,
                              const float* __restrict__ Bt,
                              const float* __restrict__ By,
                              float* __restrict__ M_out) {
  __shared__ float A[32][33];
  __shared__ float R[32][33];
  const float* B = (blockIdx.x == 0) ? Br : (blockIdx.x == 1) ? Bt : By;
  const int t = threadIdx.x;
  const int i = t >> 5, j = t & 31;
  float Lij = (j < i) ? B[i - 1 + j] : 0.0f;
  float Lji = (i < j) ? B[j - 1 + i] : 0.0f;
  float S = Lij - Lji;
  float eye = (i == j) ? 1.0f : 0.0f;
  A[i][j] = eye - S;   // I - S
  R[i][j] = eye + S;   // I + S
  __syncthreads();
  for (int p = 0; p < 32; ++p) {
    float f = A[i][p] / A[p][p];
    __syncthreads();
    if (i != p) {
      A[i][j] -= f * A[p][j];
      R[i][j] -= f * R[p][j];
    }
    __syncthreads();
  }
  // ROW-major: M_out[blk][i*32+j] = M[i][j]  (slot0=MR, slot1=MT, slot2=MY)
  M_out[blockIdx.x * 1024 + i * 32 + j] = R[i][j] / A[i][i];
}

// fp32 -> bf16 hi/lo split (hi = truncated top 16 bits; lo = next 8+ mantissa bits)
__device__ __forceinline__ void cvt_hilo8(const f32x4 f0, const f32x4 f1, s16x8& hi, s16x8& lo) {
  float f[8];
#pragma unroll
  for (int e = 0; e < 4; ++e) { f[e] = f0[e]; f[4 + e] = f1[e]; }
#pragma unroll
  for (int e = 0; e < 8; ++e) {
    unsigned u = __float_as_uint(f[e]);
    hi[e] = (short)(u >> 16);
    float ah = __uint_as_float(u & 0xffff0000u);
    lo[e] = (short)(__float_as_uint(f[e] - ah) >> 16);
  }
}

__device__ __forceinline__ void read_frag_lds(const float* sb, int off, s16x8& hi, s16x8& lo) {
  f32x4 f0 = *(const f32x4*)(sb + off);
  f32x4 f1 = *(const f32x4*)(sb + off + 4);
  cvt_hilo8(f0, f1, hi, lo);
}

// ---- dual-batch congruence  out_b = M * in_b * M^T  (shared M, independent chains) ----
// rowtile: lane holds rows i0..i0+3 (i0=(lane>>3)*4) x cols j0..j0+3 (j0=(lane&7)*4).
// Mh/Ml: A-op fragments of M; identical registers serve as B-op fragments of M^T.
__device__ __forceinline__ void congruence2(float* __restrict__ sb0, float* __restrict__ sb1,
                                            int lane,
                                            const s16x8 (&Mh)[2], const s16x8 (&Ml)[2],
                                            const f32x4 (&in0)[4], const f32x4 (&in1)[4],
                                            f32x4 (&out0)[4], f32x4 (&out1)[4]) {
  const int l15 = lane & 15, l4 = lane >> 4;
  const int i0 = (lane >> 3) << 2, j0 = (lane & 7) << 2;
  // stage inputs COL-major (stride 36): addr = col*36 + row (register transpose)
#pragma unroll
  for (int c = 0; c < 4; ++c) {
    f32x4 c0 = {in0[0][c], in0[1][c], in0[2][c], in0[3][c]};
    f32x4 c1 = {in1[0][c], in1[1][c], in1[2][c], in1[3][c]};
    *(f32x4*)(sb0 + (j0 + c) * 36 + i0) = c0;
    *(f32x4*)(sb1 + (j0 + c) * 36 + i0) = c1;
  }
  LGK();
  // B-frags: in[k][col], 8 consecutive k at col-major addr
  s16x8 Bh[2][2], Bl[2][2];
#pragma unroll
  for (int s = 0; s < 2; ++s) {
    read_frag_lds(sb0, (16 * s + l15) * 36 + 8 * l4, Bh[0][s], Bl[0][s]);
    read_frag_lds(sb1, (16 * s + l15) * 36 + 8 * l4, Bh[1][s], Bl[1][s]);
  }
  LGK();
  // g_b = M * in_b   (24 independent MFMAs)
  f32x4 g[2][2][2];
#pragma unroll
  for (int b = 0; b < 2; ++b)
#pragma unroll
    for (int ms = 0; ms < 2; ++ms)
#pragma unroll
      for (int ns = 0; ns < 2; ++ns) {
        f32x4 acc = {0.f, 0.f, 0.f, 0.f};
        acc = MFMA_B16(Ml[ms], Bh[b][ns], acc);
        acc = MFMA_B16(Mh[ms], Bl[b][ns], acc);
        acc = MFMA_B16(Mh[ms], Bh[b][ns], acc);
        g[b][ms][ns] = acc;
      }
  // stage g ROW-major
#pragma unroll
  for (int ms = 0; ms < 2; ++ms)
#pragma unroll
    for (int ns = 0; ns < 2; ++ns)
#pragma unroll
      for (int r = 0; r < 4; ++r) {
        sb0[(16 * ms + 4 * l4 + r) * 36 + 16 * ns + l15] = g[0][ms][ns][r];
        sb1[(16 * ms + 4 * l4 + r) * 36 + 16 * ns + l15] = g[1][ms][ns][r];
      }
  LGK();
  s16x8 Ah[2][2], Al[2][2];
#pragma unroll
  for (int s = 0; s < 2; ++s) {
    read_frag_lds(sb0, (16 * s + l15) * 36 + 8 * l4, Ah[0][s], Al[0][s]);
    read_frag_lds(sb1, (16 * s + l15) * 36 + 8 * l4, Ah[1][s], Al[1][s]);
  }
  LGK();
  // o_b = g_b * M^T
  f32x4 o[2][2][2];
#pragma unroll
  for (int b = 0; b < 2; ++b)
#pragma unroll
    for (int ms = 0; ms < 2; ++ms)
#pragma unroll
      for (int ns = 0; ns < 2; ++ns) {
        f32x4 acc = {0.f, 0.f, 0.f, 0.f};
        acc = MFMA_B16(Al[b][ms], Mh[ns], acc);
        acc = MFMA_B16(Ah[b][ms], Ml[ns], acc);
        acc = MFMA_B16(Ah[b][ms], Mh[ns], acc);
        o[b][ms][ns] = acc;
      }
  // C-layout -> rowtile through LDS
#pragma unroll
  for (int ms = 0; ms < 2; ++ms)
#pragma unroll
    for (int ns = 0; ns < 2; ++ns)
#pragma unroll
      for (int r = 0; r < 4; ++r) {
        sb0[(16 * ms + 4 * l4 + r) * 36 + 16 * ns + l15] = o[0][ms][ns][r];
        sb1[(16 * ms + 4 * l4 + r) * 36 + 16 * ns + l15] = o[1][ms][ns][r];
      }
  LGK();
#pragma unroll
  for (int r = 0; r < 4; ++r) {
    out0[r] = *(const f32x4*)(sb0 + (i0 + r) * 36 + j0);
    out1[r] = *(const f32x4*)(sb1 + (i0 + r) * 36 + j0);
  }
  LGK();
}

// ---------------- Kernel 2: TWO batches per wave, XCD-contiguous batch ranges, NT stores ----------------
__global__ __launch_bounds__(64) void spdsru_main(
    const float* __restrict__ X, const float* __restrict__ state,
    const float* __restrict__ WR, const float* __restrict__ Wt,
    const float* __restrict__ Wphi, const float* __restrict__ Ws,
    const float* __restrict__ Mg, float* __restrict__ out) {
  __shared__ __align__(16) float sb[2][1184];
  const int lane = threadIdx.x;
  const int l15 = lane & 15, l4 = lane >> 4;
  const int i0 = (lane >> 3) << 2, j0 = (lane & 7) << 2;
  // XCD-aware swizzle: give each XCD a CONTIGUOUS batch range (bijective, 4096 blocks).
  const int bid = blockIdx.x;
  const int batch0 = (((bid & 7) * ((NB / 2) >> 3)) + (bid >> 3)) * 2;

  // M fragments from global (row-major M)
  s16x8 Mh[3][2], Ml[3][2];
#pragma unroll
  for (int q = 0; q < 3; ++q)
#pragma unroll
    for (int s = 0; s < 2; ++s) {
      const float* p = Mg + q * 1024 + (16 * s + l15) * 32 + 8 * l4;
      cvt_hilo8(*(const f32x4*)p, *(const f32x4*)(p + 4), Mh[q][s], Ml[q][s]);
    }

  // uniform scalar weights
  const float alpha[5] = {0.01f, 0.25f, 0.5f, 0.9f, 0.99f};
  float wr[5], wsn[5];
  {
    float sR = 0.f, sS = 0.f;
#pragma unroll
    for (int a = 0; a < 5; ++a) { float v = WR[a]; wr[a] = v * v; sR += v * v; }
#pragma unroll
    for (int a = 0; a < 5; ++a) { float v = Ws[a]; wsn[a] = v * v; sS += v * v; }
    const float invR = 1.0f / (sR + EPSF), invS = 1.0f / (sS + EPSF);
#pragma unroll
    for (int a = 0; a < 5; ++a) { wr[a] *= invR; wsn[a] *= invS; }
  }
  const float wt2 = Wt[0] * Wt[0], wp2 = Wphi[0] * Wphi[0];
  const float at = wt2 / (wt2 + wp2 + EPSF);
  const float omat = 1.0f - at;

  // X in rowtile (read-once -> nontemporal load)
  const float* xp0 = X + (size_t)batch0 * 1024;
  f32x4 x0[4], x1[4];
#pragma unroll
  for (int r = 0; r < 4; ++r) {
    x0[r] = __builtin_nontemporal_load((const f32x4*)(xp0 + (i0 + r) * 32 + j0));
    x1[r] = __builtin_nontemporal_load((const f32x4*)(xp0 + 1024 + (i0 + r) * 32 + j0));
  }

  // first state pass: fold into U (Yt); keep cached (EMA re-reads from L2/L3)
  const float* stp0 = state + (size_t)batch0 * 5120;
  const float* stp1 = stp0 + 5120;
  f32x4 U0[4], U1[4];
#pragma unroll
  for (int r = 0; r < 4; ++r) { U0[r] = f32x4{0.f, 0.f, 0.f, 0.f}; U1[r] = U0[r]; }
#pragma unroll
  for (int a = 0; a < 5; ++a)
#pragma unroll
    for (int r = 0; r < 4; ++r) {
      const f32x4 v0 = *(const f32x4*)(stp0 + a * 1024 + (i0 + r) * 32 + j0);
      const f32x4 v1 = *(const f32x4*)(stp1 + a * 1024 + (i0 + r) * 32 + j0);
      U0[r] += wr[a] * v0;
      U1[r] += wr[a] * v1;
    }

  // C1: Rt = MR U MR^T ; Tt = (1-at)X + at*Rt
  f32x4 rt0[4], rt1[4];
  congruence2(sb[0], sb[1], lane, Mh[0], Ml[0], U0, U1, rt0, rt1);
  f32x4 tt0[4], tt1[4];
#pragma unroll
  for (int r = 0; r < 4; ++r) {
    tt0[r] = omat * x0[r] + at * rt0[r];
    tt1[r] = omat * x1[r] + at * rt1[r];
  }

  // C2: Phit = MT Tt MT^T
  f32x4 ph0[4], ph1[4];
  congruence2(sb[0], sb[1], lane, Mh[1], Ml[1], tt0, tt1, ph0, ph1);

  // EMA: re-read state (L2-hot), NT-write Mt, accumulate St
  float* outMt0 = out + OT_ELEMS + (size_t)batch0 * 5120;
  float* outMt1 = outMt0 + 5120;
  f32x4 st0[4], st1[4];
#pragma unroll
  for (int r = 0; r < 4; ++r) { st0[r] = f32x4{0.f, 0.f, 0.f, 0.f}; st1[r] = st0[r]; }
#pragma unroll
  for (int a = 0; a < 5; ++a) {
    const float al = alpha[a], om = 1.0f - al, ws = wsn[a];
#pragma unroll
    for (int r = 0; r < 4; ++r) {
      const f32x4 v0 = *(const f32x4*)(stp0 + a * 1024 + (i0 + r) * 32 + j0);
      const f32x4 v1 = *(const f32x4*)(stp1 + a * 1024 + (i0 + r) * 32 + j0);
      f32x4 w0 = om * v0 + al * ph0[r];
      f32x4 w1 = om * v1 + al * ph1[r];
      __builtin_nontemporal_store(w0, (f32x4*)(outMt0 + a * 1024 + (i0 + r) * 32 + j0));
      __builtin_nontemporal_store(w1, (f32x4*)(outMt1 + a * 1024 + (i0 + r) * 32 + j0));
      st0[r] += ws * w0;
      st1[r] += ws * w1;
    }
  }

  // C3: Ot = MY St MY^T
  f32x4 ot0[4], ot1[4];
  congruence2(sb[0], sb[1], lane, Mh[2], Ml[2], st0, st1, ot0, ot1);

  float* outOt0 = out + (size_t)batch0 * 1024;
#pragma unroll
  for (int r = 0; r < 4; ++r) {
    __builtin_nontemporal_store(ot0[r], (f32x4*)(outOt0 + (i0 + r) * 32 + j0));
    __builtin_nontemporal_store(ot1[r], (f32x4*)(outOt0 + 1024 + (i0 + r) * 32 + j0));
  }
}

extern "C" void kernel_launch(void* const* d_in, const int* in_sizes, int n_in,
                              void* d_out, int out_size, void* d_ws, size_t ws_size,
                              hipStream_t stream) {
  const float* X     = (const float*)d_in[0];
  const float* state = (const float*)d_in[1];
  const float* WR    = (const float*)d_in[2];
  const float* Wt    = (const float*)d_in[3];
  const float* Wphi  = (const float*)d_in[4];
  const float* Ws    = (const float*)d_in[5];
  const float* Br    = (const float*)d_in[6];
  const float* Bt    = (const float*)d_in[7];
  const float* By    = (const float*)d_in[8];
  float* m_ws = (float*)d_ws;   // 3*1024 floats: MR, MT, MY (row-major)
  float* outp = (float*)d_out;

  cayley_kernel<<<3, 1024, 0, stream>>>(Br, Bt, By, m_ws);
  spdsru_main<<<NB / 2, 64, 0, stream>>>(X, state, WR, Wt, Wphi, Ws, m_ws, outp);
}

// Round 11
// 89.090 us; speedup vs baseline: 1.2807x; 1.0617x over previous
//
#include <hip/hip_runtime.h>

#define NB 8192
#define OT_ELEMS (NB * 1024)   // floats of Ot, then Mt
#define EPSF 1e-10f

typedef __attribute__((ext_vector_type(4))) float f32x4;
typedef __attribute__((ext_vector_type(8))) short s16x8;   // 8 bf16 (4 VGPRs)

// Wave-local DS phase fence WITHOUT "memory" clobber (R9/R10 replay-proven):
// sched_barrier(0) pins compile-time order; lgkmcnt(0) drains only LDS queue;
// global loads/stores previously issued stay in flight across the fence.
#define SBAR() __builtin_amdgcn_sched_barrier(0)
#define LGK()  do { SBAR(); asm volatile("s_waitcnt lgkmcnt(0)"); SBAR(); } while (0)

#define MFMA_B16(A, B, C) __builtin_amdgcn_mfma_f32_16x16x32_bf16((A), (B), (C), 0, 0, 0)

// ---------------- Kernel 1: Cayley matrices M = (I-S)^-1 (I+S), stored ROW-major ----------------
__global__ void cayley_kernel(const float* __restrict__ Br,
                              const float* __restrict__ Bt,
                              const float* __restrict__ By,
                              float* __restrict__ M_out) {
  __shared__ float A[32][33];
  __shared__ float R[32][33];
  const float* B = (blockIdx.x == 0) ? Br : (blockIdx.x == 1) ? Bt : By;
  const int t = threadIdx.x;
  const int i = t >> 5, j = t & 31;
  float Lij = (j < i) ? B[i - 1 + j] : 0.0f;
  float Lji = (i < j) ? B[j - 1 + i] : 0.0f;
  float S = Lij - Lji;
  float eye = (i == j) ? 1.0f : 0.0f;
  A[i][j] = eye - S;   // I - S
  R[i][j] = eye + S;   // I + S
  __syncthreads();
  for (int p = 0; p < 32; ++p) {
    float f = A[i][p] / A[p][p];
    __syncthreads();
    if (i != p) {
      A[i][j] -= f * A[p][j];
      R[i][j] -= f * R[p][j];
    }
    __syncthreads();
  }
  // ROW-major: slot0=MR(0), slot1=MT(1024), slot2=MY(2048)
  M_out[blockIdx.x * 1024 + i * 32 + j] = R[i][j] / A[i][i];
}

// ---------------- Kernel 1b: P = MT*MR (fp32), ROW-major into ws slot 3 ----------------
__global__ void combine_kernel(float* __restrict__ ws) {
  __shared__ float sMR[1024], sMT[1024];
  const int t = threadIdx.x;
  sMR[t] = ws[t];
  sMT[t] = ws[1024 + t];
  __syncthreads();
  const int i = t >> 5, j = t & 31;
  float s = 0.f;
#pragma unroll
  for (int k = 0; k < 32; ++k)
    s = fmaf(sMT[i * 32 + k], sMR[k * 32 + j], s);
  ws[3072 + i * 32 + j] = s;   // P row-major
}

// fp32 -> bf16 hi/lo split (hi = truncated top 16 bits; lo = next 8+ mantissa bits)
__device__ __forceinline__ void cvt_hilo8(const f32x4 f0, const f32x4 f1, s16x8& hi, s16x8& lo) {
  float f[8];
#pragma unroll
  for (int e = 0; e < 4; ++e) { f[e] = f0[e]; f[4 + e] = f1[e]; }
#pragma unroll
  for (int e = 0; e < 8; ++e) {
    unsigned u = __float_as_uint(f[e]);
    hi[e] = (short)(u >> 16);
    float ah = __uint_as_float(u & 0xffff0000u);
    lo[e] = (short)(__float_as_uint(f[e] - ah) >> 16);
  }
}

__device__ __forceinline__ void read_frag_lds(const float* sb, int off, s16x8& hi, s16x8& lo) {
  f32x4 f0 = *(const f32x4*)(sb + off);
  f32x4 f1 = *(const f32x4*)(sb + off + 4);
  cvt_hilo8(f0, f1, hi, lo);
}

// ---------------- Kernel 2: one batch per wave; phase-collapsed pipeline ----------------
// Algebra: P = MT*MR. Phit = (1-at)*MT X MT^T + at*P U P^T  (stage A, dual-chain).
// St = V' + cP*Phit, V' = sum wsn[a](1-al[a])*m[a], cP = sum wsn[a]*al[a].
// Ot = MY St MY^T (stage B).  Mt[a] = (1-al)*m[a](re-read) + al*Phit — EMA loads
// issued before stage B, consumed mid-stage-B (off critical path).
__global__ __launch_bounds__(64) void spdsru_main(
    const float* __restrict__ X, const float* __restrict__ state,
    const float* __restrict__ WR, const float* __restrict__ Wt,
    const float* __restrict__ Wphi, const float* __restrict__ Ws,
    const float* __restrict__ Mg, float* __restrict__ out) {
  __shared__ __align__(16) float sb0[1184];
  __shared__ __align__(16) float sb1[1184];
  const int lane = threadIdx.x;
  const int l15 = lane & 15, l4 = lane >> 4;
  const int i0 = (lane >> 3) << 2, j0 = (lane & 7) << 2;
  // XCD-contiguous swizzle (8192 blocks): xcd = bid&7 owns batches [xcd*1024, ...)
  const int bid = blockIdx.x;
  const int batch = (bid & 7) * (NB >> 3) + (bid >> 3);

  // M fragments: q=0 -> MT (slot1), q=1 -> P (slot3), q=2 -> MY (slot2)
  s16x8 Mh[3][2], Ml[3][2];
  {
    const int srcoff[3] = {1024, 3072, 2048};
#pragma unroll
    for (int q = 0; q < 3; ++q)
#pragma unroll
      for (int s = 0; s < 2; ++s) {
        const float* p = Mg + srcoff[q] + (16 * s + l15) * 32 + 8 * l4;
        cvt_hilo8(*(const f32x4*)p, *(const f32x4*)(p + 4), Mh[q][s], Ml[q][s]);
      }
  }

  // uniform scalar weights
  const float alpha[5] = {0.01f, 0.25f, 0.5f, 0.9f, 0.99f};
  float wr[5], va[5];
  float cP = 0.f;
  {
    float sR = 0.f, sS = 0.f, wq[5];
#pragma unroll
    for (int a = 0; a < 5; ++a) { float v = WR[a]; wr[a] = v * v; sR += v * v; }
#pragma unroll
    for (int a = 0; a < 5; ++a) { float v = Ws[a]; wq[a] = v * v; sS += v * v; }
    const float invR = 1.0f / (sR + EPSF), invS = 1.0f / (sS + EPSF);
#pragma unroll
    for (int a = 0; a < 5; ++a) {
      wr[a] *= invR;
      float w = wq[a] * invS;
      va[a] = w * (1.0f - alpha[a]);
      cP += w * alpha[a];
    }
  }
  const float wt2 = Wt[0] * Wt[0], wp2 = Wphi[0] * Wphi[0];
  const float at = wt2 / (wt2 + wp2 + EPSF);
  const float omat = 1.0f - at;

  // loads: X (NT) + state pass 1 (rowtile); fold U (Yt) and V'
  const float* xp = X + (size_t)batch * 1024;
  f32x4 x[4];
#pragma unroll
  for (int r = 0; r < 4; ++r)
    x[r] = __builtin_nontemporal_load((const f32x4*)(xp + (i0 + r) * 32 + j0));

  const float* stp = state + (size_t)batch * 5120;
  f32x4 U[4], V[4];
#pragma unroll
  for (int r = 0; r < 4; ++r) { U[r] = f32x4{0.f, 0.f, 0.f, 0.f}; V[r] = U[r]; }
#pragma unroll
  for (int a = 0; a < 5; ++a)
#pragma unroll
    for (int r = 0; r < 4; ++r) {
      const f32x4 v = *(const f32x4*)(stp + a * 1024 + (i0 + r) * 32 + j0);
      U[r] += wr[a] * v;
      V[r] += va[a] * v;
    }

  // ---- Stage A: dual-chain congruence (X with MT) || (U with P) ----
#pragma unroll
  for (int c = 0; c < 4; ++c) {
    f32x4 cx = {x[0][c], x[1][c], x[2][c], x[3][c]};
    f32x4 cu = {U[0][c], U[1][c], U[2][c], U[3][c]};
    *(f32x4*)(sb0 + (j0 + c) * 36 + i0) = cx;   // X col-major
    *(f32x4*)(sb1 + (j0 + c) * 36 + i0) = cu;   // U col-major
  }
  LGK();
  s16x8 BXh[2], BXl[2], BUh[2], BUl[2];
#pragma unroll
  for (int s = 0; s < 2; ++s) {
    read_frag_lds(sb0, (16 * s + l15) * 36 + 8 * l4, BXh[s], BXl[s]);
    read_frag_lds(sb1, (16 * s + l15) * 36 + 8 * l4, BUh[s], BUl[s]);
  }
  LGK();
  f32x4 gX[2][2], gU[2][2];
#pragma unroll
  for (int ms = 0; ms < 2; ++ms)
#pragma unroll
    for (int ns = 0; ns < 2; ++ns) {
      f32x4 a0 = {0.f, 0.f, 0.f, 0.f};
      a0 = MFMA_B16(Ml[0][ms], BXh[ns], a0);
      a0 = MFMA_B16(Mh[0][ms], BXl[ns], a0);
      a0 = MFMA_B16(Mh[0][ms], BXh[ns], a0);
      gX[ms][ns] = a0;
      f32x4 a1 = {0.f, 0.f, 0.f, 0.f};
      a1 = MFMA_B16(Ml[1][ms], BUh[ns], a1);
      a1 = MFMA_B16(Mh[1][ms], BUl[ns], a1);
      a1 = MFMA_B16(Mh[1][ms], BUh[ns], a1);
      gU[ms][ns] = a1;
    }
#pragma unroll
  for (int ms = 0; ms < 2; ++ms)
#pragma unroll
    for (int ns = 0; ns < 2; ++ns)
#pragma unroll
      for (int r = 0; r < 4; ++r) {
        sb0[(16 * ms + 4 * l4 + r) * 36 + 16 * ns + l15] = gX[ms][ns][r];
        sb1[(16 * ms + 4 * l4 + r) * 36 + 16 * ns + l15] = gU[ms][ns][r];
      }
  LGK();
  s16x8 AXh[2], AXl[2], AUh[2], AUl[2];
#pragma unroll
  for (int s = 0; s < 2; ++s) {
    read_frag_lds(sb0, (16 * s + l15) * 36 + 8 * l4, AXh[s], AXl[s]);
    read_frag_lds(sb1, (16 * s + l15) * 36 + 8 * l4, AUh[s], AUl[s]);
  }
  LGK();
  f32x4 ph[2][2];   // Phit in C-layout
#pragma unroll
  for (int ms = 0; ms < 2; ++ms)
#pragma unroll
    for (int ns = 0; ns < 2; ++ns) {
      f32x4 a0 = {0.f, 0.f, 0.f, 0.f};
      a0 = MFMA_B16(AXl[ms], Mh[0][ns], a0);
      a0 = MFMA_B16(AXh[ms], Ml[0][ns], a0);
      a0 = MFMA_B16(AXh[ms], Mh[0][ns], a0);
      f32x4 a1 = {0.f, 0.f, 0.f, 0.f};
      a1 = MFMA_B16(AUl[ms], Mh[1][ns], a1);
      a1 = MFMA_B16(AUh[ms], Ml[1][ns], a1);
      a1 = MFMA_B16(AUh[ms], Mh[1][ns], a1);
      ph[ms][ns] = omat * a0 + at * a1;
    }

  // ---- Phit C-layout -> rowtile (needed for EMA stores + St fold) ----
#pragma unroll
  for (int ms = 0; ms < 2; ++ms)
#pragma unroll
    for (int ns = 0; ns < 2; ++ns)
#pragma unroll
      for (int r = 0; r < 4; ++r)
        sb0[(16 * ms + 4 * l4 + r) * 36 + 16 * ns + l15] = ph[ms][ns][r];
  LGK();
  f32x4 ph4[4];
#pragma unroll
  for (int r = 0; r < 4; ++r)
    ph4[r] = *(const f32x4*)(sb0 + (i0 + r) * 36 + j0);
  LGK();

  // St = V' + cP*Phit (rowtile); stage into sb0 col-major for stage B
  f32x4 st4[4];
#pragma unroll
  for (int r = 0; r < 4; ++r) st4[r] = V[r] + cP * ph4[r];
#pragma unroll
  for (int c = 0; c < 4; ++c) {
    f32x4 cs = {st4[0][c], st4[1][c], st4[2][c], st4[3][c]};
    *(f32x4*)(sb0 + (j0 + c) * 36 + i0) = cs;
  }
  // ---- EMA ISSUE: re-read state (L2-hot) into regs; consumed mid-stage-B ----
  f32x4 raw[20];
#pragma unroll
  for (int a = 0; a < 5; ++a)
#pragma unroll
    for (int r = 0; r < 4; ++r)
      raw[a * 4 + r] = *(const f32x4*)(stp + a * 1024 + (i0 + r) * 32 + j0);
  LGK();

  // ---- Stage B: Ot = MY St MY^T ----
  s16x8 BSh[2], BSl[2];
#pragma unroll
  for (int s = 0; s < 2; ++s)
    read_frag_lds(sb0, (16 * s + l15) * 36 + 8 * l4, BSh[s], BSl[s]);
  LGK();
  f32x4 gS[2][2];
#pragma unroll
  for (int ms = 0; ms < 2; ++ms)
#pragma unroll
    for (int ns = 0; ns < 2; ++ns) {
      f32x4 acc = {0.f, 0.f, 0.f, 0.f};
      acc = MFMA_B16(Ml[2][ms], BSh[ns], acc);
      acc = MFMA_B16(Mh[2][ms], BSl[ns], acc);
      acc = MFMA_B16(Mh[2][ms], BSh[ns], acc);
      gS[ms][ns] = acc;
    }
  // ---- EMA CONSUME: Mt[a] = (1-al)*raw + al*Phit, NT store (overlaps stage B) ----
  float* outMt = out + OT_ELEMS + (size_t)batch * 5120;
#pragma unroll
  for (int a = 0; a < 5; ++a) {
    const float al = alpha[a], om = 1.0f - al;
#pragma unroll
    for (int r = 0; r < 4; ++r) {
      f32x4 w = om * raw[a * 4 + r] + al * ph4[r];
      __builtin_nontemporal_store(w, (f32x4*)(outMt + a * 1024 + (i0 + r) * 32 + j0));
    }
  }
#pragma unroll
  for (int ms = 0; ms < 2; ++ms)
#pragma unroll
    for (int ns = 0; ns < 2; ++ns)
#pragma unroll
      for (int r = 0; r < 4; ++r)
        sb0[(16 * ms + 4 * l4 + r) * 36 + 16 * ns + l15] = gS[ms][ns][r];
  LGK();
  s16x8 ASh[2], ASl[2];
#pragma unroll
  for (int s = 0; s < 2; ++s)
    read_frag_lds(sb0, (16 * s + l15) * 36 + 8 * l4, ASh[s], ASl[s]);
  LGK();
  f32x4 o[2][2];
#pragma unroll
  for (int ms = 0; ms < 2; ++ms)
#pragma unroll
    for (int ns = 0; ns < 2; ++ns) {
      f32x4 acc = {0.f, 0.f, 0.f, 0.f};
      acc = MFMA_B16(ASl[ms], Mh[2][ns], acc);
      acc = MFMA_B16(ASh[ms], Ml[2][ns], acc);
      acc = MFMA_B16(ASh[ms], Mh[2][ns], acc);
      o[ms][ns] = acc;
    }
#pragma unroll
  for (int ms = 0; ms < 2; ++ms)
#pragma unroll
    for (int ns = 0; ns < 2; ++ns)
#pragma unroll
      for (int r = 0; r < 4; ++r)
        sb0[(16 * ms + 4 * l4 + r) * 36 + 16 * ns + l15] = o[ms][ns][r];
  LGK();
  float* outOt = out + (size_t)batch * 1024;
#pragma unroll
  for (int r = 0; r < 4; ++r) {
    f32x4 ov = *(const f32x4*)(sb0 + (i0 + r) * 36 + j0);
    __builtin_nontemporal_store(ov, (f32x4*)(outOt + (i0 + r) * 32 + j0));
  }
}

extern "C" void kernel_launch(void* const* d_in, const int* in_sizes, int n_in,
                              void* d_out, int out_size, void* d_ws, size_t ws_size,
                              hipStream_t stream) {
  const float* X     = (const float*)d_in[0];
  const float* state = (const float*)d_in[1];
  const float* WR    = (const float*)d_in[2];
  const float* Wt    = (const float*)d_in[3];
  const float* Wphi  = (const float*)d_in[4];
  const float* Ws    = (const float*)d_in[5];
  const float* Br    = (const float*)d_in[6];
  const float* Bt    = (const float*)d_in[7];
  const float* By    = (const float*)d_in[8];
  float* m_ws = (float*)d_ws;   // 4*1024 floats: MR, MT, MY, P (row-major)
  float* outp = (float*)d_out;

  cayley_kernel<<<3, 1024, 0, stream>>>(Br, Bt, By, m_ws);
  combine_kernel<<<1, 1024, 0, stream>>>(m_ws);
  spdsru_main<<<NB, 64, 0, stream>>>(X, state, WR, Wt, Wphi, Ws, m_ws, outp);
}